// Round 7
// baseline (821.313 us; speedup 1.0000x reference)
//
#include <hip/hip_runtime.h>
#include <hip/hip_bf16.h>
#include <hip/hip_cooperative_groups.h>
#include <math.h>

namespace cg = cooperative_groups;

#define N_NODES 100000
#define N_EDGES 1600000
#define ET (N_EDGES + N_NODES)   // edges + self-loops
#define N_GRAPHS 512
#define NEG_SLOPE 0.2f
#define G2_BLOCKS 1280           // legacy k_gat2 grid (fallback path)

// ---- bucketed CSR params ----
#define BSH 7                                 // 128 nodes per bucket
#define NDB 128                               // dsts per bucket
#define NBUCK ((N_NODES + NDB - 1) / NDB)     // 782
#define BCAP 2560                             // bucket capacity (mean 2174, +8 sigma)
#define ABLK 512                              // binA sub-grid
#define CHUNK ((ET + ABLK - 1) / ABLK)        // 3321 edges per binA block
#define F1_OFF (ABLK + 3)                     // feat1 blocks start here in k_pre
#define PRE_GRID (F1_OFF + 1536)              // 2051
#define SRC_MASK 131071u                      // low 17 bits = src id

// binA LDS: pairs (CHUNK*4) + hist/gbase/cnt2 (NBUCK each) + excl (NBUCK+1) + red (256)
#define BINA_SMEM (CHUNK * 4 + NBUCK * 4 * 4 + 4 + 1024)   // 26824 B

__device__ __forceinline__ void atomAddF(float* p, float v) { unsafeAtomicAdd(p, v); }
__device__ __forceinline__ float lrelu(float v) { return v >= 0.f ? v : NEG_SLOPE * v; }

__device__ __forceinline__ unsigned short f2bf(float f) {
    unsigned int u = __float_as_uint(f);
    u += 0x7FFFu + ((u >> 16) & 1u);
    return (unsigned short)(u >> 16);
}
__device__ __forceinline__ float bf2f(unsigned short s) { return __uint_as_float(((unsigned int)s) << 16); }
__device__ __forceinline__ float bflo(unsigned int p) { return __uint_as_float(p << 16); }
__device__ __forceinline__ float bfhi(unsigned int p) { return __uint_as_float(p & 0xFFFF0000u); }

// ============ Launch 1: binA (blocks 0..ABLK-1) + wv/init + feat1 =========
__global__ __launch_bounds__(256) void k_pre(
    const int* __restrict__ ei, unsigned* __restrict__ gbuf, int* __restrict__ bcur,
    const float* __restrict__ x, const float* __restrict__ W1,
    const float* __restrict__ as1, const float* __restrict__ ad1,
    const float* __restrict__ W2, const float* __restrict__ as2,
    const float* __restrict__ ad2, const float* __restrict__ Wg,
    const float* __restrict__ b2, const float* __restrict__ bg,
    unsigned short* __restrict__ h1p, unsigned short* __restrict__ a1sh,
    float* __restrict__ a1d, float* __restrict__ wv, float* __restrict__ out)
{
    __shared__ __align__(16) char smem[BINA_SMEM];
    const int t = threadIdx.x;
    const int blk = blockIdx.x;

    if (blk >= ABLK && blk < F1_OFF) {
        // ---- misc: wv precompute / out init ----
        const int bb = blk - ABLK;
        if (bb == 0) {
            if (t < 192) {
                int c = t & 63, which = t >> 6;
                const float* v = (which == 0) ? Wg : ((which == 1) ? as2 : ad2);
                float s = 0.f;
                #pragma unroll
                for (int k = 0; k < 128; ++k) s += W2[c * 128 + k] * v[k];
                wv[which * 64 + c] = s;
            } else if (t == 192) {
                float s = 0.f;
                #pragma unroll
                for (int k = 0; k < 128; ++k) s += b2[k] * Wg[k];
                wv[192] = s;
            }
        } else {
            int i = (bb - 1) * 256 + t;
            if (i < N_GRAPHS) out[i] = bg[0];
        }
        return;
    }

    if (blk >= F1_OFF) {
        // ---- feat1 (persistent over node groups; original VGPR-52 form) ----
        float (*xs)[76] = (float (*)[76])smem;
        const int g = t >> 6;
        const int c = t & 63;
        const int vb = blk - F1_OFF;
        const int fstride = PRE_GRID - F1_OFF;
        for (int nb = vb; nb < N_NODES / 4; nb += fstride) {
            const int n = nb * 4 + g;
            const float* xr = x + (long)n * 75;
            xs[g][c] = xr[c];
            if (c < 11) xs[g][64 + c] = xr[64 + c];
            __syncthreads();
            float h = 0.f;
            #pragma unroll
            for (int k = 0; k < 75; ++k) h += xs[g][k] * W1[k * 64 + c];
            h1p[(long)n * 64 + c] = f2bf(h);
            const int head = c >> 3, lane = c & 7;
            float vs = h * as1[c];
            float vd = h * ad1[c];
            #pragma unroll
            for (int off = 1; off < 8; off <<= 1) {
                vs += __shfl_xor(vs, off, 64);
                vd += __shfl_xor(vd, off, 64);
            }
            if (lane == 0) { a1sh[n * 8 + head] = f2bf(vs); a1d[n * 8 + head] = vd; }
            __syncthreads();
        }
        return;
    }

    // ---- binA: per-chunk LDS counting sort by bucket (packed 4-B entries) ----
    unsigned* pairs = (unsigned*)smem;                 // CHUNK x 4 B: (dl<<17)|src
    int* hist  = (int*)(smem + CHUNK * 4);             // NBUCK
    int* excl  = hist + NBUCK;                         // NBUCK + 1
    int* gbase = excl + NBUCK + 1;                     // NBUCK
    int* cnt2  = gbase + NBUCK;                        // NBUCK
    int* red   = cnt2 + NBUCK;                         // 256
    const long e0 = (long)blk * CHUNK;
    const int  n  = (int)((e0 + CHUNK <= ET) ? CHUNK : (ET - e0));
    for (int i = t; i < NBUCK; i += 256) { hist[i] = 0; cnt2[i] = 0; }
    __syncthreads();
    for (int i = t; i < n; i += 256) {
        long e = e0 + i;
        int dst = (e < N_EDGES) ? ei[N_EDGES + e] : (int)(e - N_EDGES);
        atomicAdd(&hist[dst >> BSH], 1);
    }
    __syncthreads();
    // two-level parallel exclusive scan of hist[NBUCK] (4 buckets/thread)
    {
        int lk[4]; int s = 0;
        #pragma unroll
        for (int k = 0; k < 4; ++k) {
            int idx = t * 4 + k;
            int v = (idx < NBUCK) ? hist[idx] : 0;
            lk[k] = s; s += v;
        }
        red[t] = s;
        __syncthreads();
        for (int off = 1; off < 256; off <<= 1) {
            int a = (t >= off) ? red[t - off] : 0;
            __syncthreads();
            red[t] += a;
            __syncthreads();
        }
        int p = red[t] - s;   // exclusive prefix of this thread's chunk
        #pragma unroll
        for (int k = 0; k < 4; ++k) {
            int idx = t * 4 + k;
            if (idx < NBUCK) excl[idx] = p + lk[k];
        }
    }
    if (t == 0) excl[NBUCK] = n;
    __syncthreads();
    for (int i = t; i < n; i += 256) {
        long e = e0 + i;
        int src, dst;
        if (e < N_EDGES) { src = ei[e]; dst = ei[N_EDGES + e]; }
        else             { src = dst = (int)(e - N_EDGES); }
        int b = dst >> BSH;
        int pos = excl[b] + atomicAdd(&cnt2[b], 1);
        pairs[pos] = ((unsigned)(dst & (NDB - 1)) << 17) | (unsigned)src;
    }
    __syncthreads();
    for (int b = t; b < NBUCK; b += 256)
        gbase[b] = hist[b] ? atomicAdd(&bcur[b], hist[b]) : 0;
    __syncthreads();
    // flush: bucket-per-thread run copies
    for (int b = t; b < NBUCK; b += 256) {
        const int s = excl[b], e2 = excl[b + 1];
        if (s == e2) continue;
        unsigned* gp = gbuf + (long)b * BCAP + gbase[b];
        for (int i = s; i < e2; ++i) gp[i - s] = pairs[i];
    }
}

// ---- shared gather macros (5-deep pipeline) ------------------------------
#define SLOT_INIT(k) \
    bool v##k = (k < dgl); \
    int s##k = v##k ? lds_src[beg + k] : 0; \
    unsigned short ab##k = a1sh[(long)s##k * 8 + l]; \
    uint4 pv##k = *(const uint4*)(h1p + (long)s##k * 64 + l * 8);

#define SLOT_STEP(k) { \
    float ee = v##k ? __expf(lrelu(bf2f(ab##k) + adh)) : 0.f; \
    den += ee; \
    acc[0] += ee * bflo(pv##k.x); acc[1] += ee * bfhi(pv##k.x); \
    acc[2] += ee * bflo(pv##k.y); acc[3] += ee * bfhi(pv##k.y); \
    acc[4] += ee * bflo(pv##k.z); acc[5] += ee * bfhi(pv##k.z); \
    acc[6] += ee * bflo(pv##k.w); acc[7] += ee * bfhi(pv##k.w); \
    v##k = (j + 5 + k) < dgl; \
    int sn = v##k ? lds_src[beg + j + 5 + k] : 0; \
    ab##k = a1sh[(long)sn * 8 + l]; \
    pv##k = *(const uint4*)(h1p + (long)sn * 64 + l * 8); }

// ====== FUSED: binB build + conv1 gather + grid.sync + conv2/pool =========
__global__ __launch_bounds__(512, 8) void k_gat12(
    const unsigned* __restrict__ gbuf, const int* __restrict__ bcur,
    const unsigned short* __restrict__ a1sh, const float* __restrict__ a1d,
    const unsigned short* __restrict__ h1p, const float* __restrict__ bias1,
    const float* __restrict__ wv,
    float2* __restrict__ sg2, float* __restrict__ a2dv,
    const int* __restrict__ batch, float* __restrict__ out)
{
    __shared__ int lds_src[BCAP];
    __shared__ int hist[NDB], excl[NDB + 1], cnt2[NDB];
    __shared__ int red[512];
    const int t = threadIdx.x;
    const int b = blockIdx.x;
    const int d0 = b << BSH;
    const int nloc = (N_NODES - d0 < NDB) ? (N_NODES - d0) : NDB;
    int cntr = bcur[b];
    const int cnt = cntr < BCAP ? cntr : BCAP;

    // ---- Phase A: local histogram + scan + LDS scatter (no global CSR) ----
    if (t < NDB) { hist[t] = 0; cnt2[t] = 0; }
    __syncthreads();
    const unsigned* eb = gbuf + (long)b * BCAP;
    for (int i = t; i < cnt; i += 512) atomicAdd(&hist[eb[i] >> 17], 1);
    __syncthreads();
    {
        int v = (t < NDB) ? hist[t] : 0;
        if (t < NDB) red[t] = v;
        __syncthreads();
        for (int off = 1; off < NDB; off <<= 1) {
            int a = (t < NDB && t >= off) ? red[t - off] : 0;
            __syncthreads();
            if (t < NDB) red[t] += a;
            __syncthreads();
        }
        if (t < nloc) excl[t] = red[t] - v;
        if (t == 0) excl[nloc] = cnt;
    }
    __syncthreads();
    for (int i = t; i < cnt; i += 512) {
        unsigned pr = eb[i];
        int dl = (int)(pr >> 17);
        int slot = excl[dl] + atomicAdd(&cnt2[dl], 1);
        lds_src[slot] = (int)(pr & SRC_MASK);
    }
    __syncthreads();

    // ---- Phase B: conv1 gather (lane l = head l; 5-deep pipeline) ----
    const int l = t & 7;
    const int gid = t >> 3;                  // 0..63 groups
    for (int dl = gid; dl < nloc; dl += 64) {
        const int dst = d0 + dl;
        const int beg = excl[dl];
        const int dgl = excl[dl + 1] - beg;  // >= 1 (self-loop)
        const float adh = a1d[(long)dst * 8 + l];

        float acc[8] = {0.f,0.f,0.f,0.f,0.f,0.f,0.f,0.f};
        float den = 0.f;

        SLOT_INIT(0) SLOT_INIT(1) SLOT_INIT(2) SLOT_INIT(3) SLOT_INIT(4)

        for (int j = 0; j < dgl; j += 5) {
            SLOT_STEP(0) SLOT_STEP(1) SLOT_STEP(2) SLOT_STEP(3) SLOT_STEP(4)
        }

        const float inv = 1.f / den;
        float pg = 0.f, ps = 0.f, pd = 0.f;
        #pragma unroll
        for (int k = 0; k < 8; ++k) {
            float vv = acc[k] * inv + bias1[l * 8 + k];
            vv = vv > 0.f ? vv : (__expf(vv) - 1.f);      // elu -> x2 channel
            pg += vv * wv[l * 8 + k];
            ps += vv * wv[64 + l * 8 + k];
            pd += vv * wv[128 + l * 8 + k];
        }
        #pragma unroll
        for (int off = 1; off < 8; off <<= 1) {
            pg += __shfl_xor(pg, off, 64);
            ps += __shfl_xor(ps, off, 64);
            pd += __shfl_xor(pd, off, 64);
        }
        if (l == 0) { sg2[dst] = make_float2(ps, pg); a2dv[dst] = pd; }
    }

    // ---- grid-wide barrier (cross-XCD visibility of sg2/a2dv) ----
    __threadfence();
    cg::this_grid().sync();
    __threadfence();

    // ---- Phase C: conv2 + pool for THIS bucket's nodes; edges from LDS ----
    const int sl = t & 15;
    const int sg = t >> 4;                   // 0..31 subgroups
    const float bc = wv[192];
    float accg = 0.f;
    int curg = -1;
    for (int q = 0; q < 4; ++q) {
        const int dl = sg * 4 + q;
        if (dl >= nloc) break;
        const int n = d0 + dl;
        const int beg = excl[dl], end = excl[dl + 1];
        const float adv = a2dv[n];
        float num = 0.f, den = 0.f;
        for (int j = beg + sl; j < end; j += 16) {
            int s = lds_src[j];
            float2 v = sg2[s];
            float ee = __expf(lrelu(v.x + adv));
            den += ee;
            num += ee * v.y;
        }
        #pragma unroll
        for (int off = 1; off < 16; off <<= 1) {
            den += __shfl_xor(den, off, 64);
            num += __shfl_xor(num, off, 64);
        }
        if (sl == 0) {
            int gr = batch[n];
            if (gr != curg) {
                if (curg >= 0) atomAddF(out + curg, accg);
                curg = gr; accg = 0.f;
            }
            accg += num / den + bc;
        }
    }
    if (sl == 0 && curg >= 0) atomAddF(out + curg, accg);
}

// ====== LEGACY fallback pair (used only if cooperative launch fails) ======
__global__ __launch_bounds__(512) void k_gat1(
    const unsigned* __restrict__ gbuf, const int* __restrict__ bcur,
    int* __restrict__ rowptr, int* __restrict__ ecol,
    const unsigned short* __restrict__ a1sh, const float* __restrict__ a1d,
    const unsigned short* __restrict__ h1p, const float* __restrict__ bias1,
    const float* __restrict__ wv,
    float2* __restrict__ sg2, float* __restrict__ a2dv)
{
    __shared__ int lds_src[BCAP];
    __shared__ int hist[NDB], excl[NDB + 1], cnt2[NDB];
    __shared__ int red[512];
    const int t = threadIdx.x;
    const int b = blockIdx.x;
    const int d0 = b << BSH;
    const int nloc = (N_NODES - d0 < NDB) ? (N_NODES - d0) : NDB;
    int cntr = bcur[b];
    const int cnt = cntr < BCAP ? cntr : BCAP;

    int partial = 0;
    for (int i = t; i < b; i += 512) partial += bcur[i];
    red[t] = partial;
    __syncthreads();
    for (int off = 256; off > 0; off >>= 1) {
        if (t < off) red[t] += red[t + off];
        __syncthreads();
    }
    const int base = red[0];
    __syncthreads();

    if (t < NDB) { hist[t] = 0; cnt2[t] = 0; }
    __syncthreads();
    const unsigned* eb = gbuf + (long)b * BCAP;
    for (int i = t; i < cnt; i += 512) atomicAdd(&hist[eb[i] >> 17], 1);
    __syncthreads();
    {
        int v = (t < NDB) ? hist[t] : 0;
        if (t < NDB) red[t] = v;
        __syncthreads();
        for (int off = 1; off < NDB; off <<= 1) {
            int a = (t < NDB && t >= off) ? red[t - off] : 0;
            __syncthreads();
            if (t < NDB) red[t] += a;
            __syncthreads();
        }
        if (t < nloc) excl[t] = red[t] - v;
        if (t == 0) excl[nloc] = cnt;
    }
    __syncthreads();
    if (t < nloc) rowptr[d0 + t] = base + excl[t];
    if (b == NBUCK - 1 && t == 0) rowptr[N_NODES] = base + cnt;
    for (int i = t; i < cnt; i += 512) {
        unsigned pr = eb[i];
        int dl = (int)(pr >> 17);
        int slot = excl[dl] + atomicAdd(&cnt2[dl], 1);
        lds_src[slot] = (int)(pr & SRC_MASK);
    }
    __syncthreads();
    for (int i = t; i < cnt; i += 512) ecol[base + i] = lds_src[i];

    const int l = t & 7;
    const int gid = t >> 3;
    for (int dl = gid; dl < nloc; dl += 64) {
        const int dst = d0 + dl;
        const int beg = excl[dl];
        const int dgl = excl[dl + 1] - beg;
        const float adh = a1d[(long)dst * 8 + l];

        float acc[8] = {0.f,0.f,0.f,0.f,0.f,0.f,0.f,0.f};
        float den = 0.f;

        SLOT_INIT(0) SLOT_INIT(1) SLOT_INIT(2) SLOT_INIT(3) SLOT_INIT(4)

        for (int j = 0; j < dgl; j += 5) {
            SLOT_STEP(0) SLOT_STEP(1) SLOT_STEP(2) SLOT_STEP(3) SLOT_STEP(4)
        }

        const float inv = 1.f / den;
        float pg = 0.f, ps = 0.f, pd = 0.f;
        #pragma unroll
        for (int k = 0; k < 8; ++k) {
            float vv = acc[k] * inv + bias1[l * 8 + k];
            vv = vv > 0.f ? vv : (__expf(vv) - 1.f);
            pg += vv * wv[l * 8 + k];
            ps += vv * wv[64 + l * 8 + k];
            pd += vv * wv[128 + l * 8 + k];
        }
        #pragma unroll
        for (int off = 1; off < 8; off <<= 1) {
            pg += __shfl_xor(pg, off, 64);
            ps += __shfl_xor(ps, off, 64);
            pd += __shfl_xor(pd, off, 64);
        }
        if (l == 0) { sg2[dst] = make_float2(ps, pg); a2dv[dst] = pd; }
    }
}

__global__ __launch_bounds__(256) void k_gat2(
    const int* __restrict__ rowptr, const int* __restrict__ ecol,
    const float2* __restrict__ sg2, const float* __restrict__ a2dv,
    const float* __restrict__ wv, const int* __restrict__ batch,
    float* __restrict__ out)
{
    const int sl = threadIdx.x & 15;
    const int sgid = ((blockIdx.x * 256 + threadIdx.x) >> 4);
    const int NS = G2_BLOCKS * 16;
    const int per = (N_NODES + NS - 1) / NS;
    const int n0 = sgid * per;
    const int n1 = min(n0 + per, N_NODES);
    const float bc = wv[192];

    float accg = 0.f;
    int curg = -1;
    for (int n = n0; n < n1; ++n) {
        const int beg = rowptr[n], end = rowptr[n + 1];
        const float adv = a2dv[n];
        float num = 0.f, den = 0.f;
        for (int j = beg + sl; j < end; j += 16) {
            int s = ecol[j];
            float2 v = sg2[s];
            float ee = __expf(lrelu(v.x + adv));
            den += ee;
            num += ee * v.y;
        }
        #pragma unroll
        for (int off = 1; off < 16; off <<= 1) {
            den += __shfl_xor(den, off, 64);
            num += __shfl_xor(num, off, 64);
        }
        if (sl == 0) {
            int gr = batch[n];
            if (gr != curg) {
                if (curg >= 0) atomAddF(out + curg, accg);
                curg = gr; accg = 0.f;
            }
            accg += num / den + bc;
        }
    }
    if (sl == 0 && curg >= 0) atomAddF(out + curg, accg);
}

extern "C" void kernel_launch(void* const* d_in, const int* in_sizes, int n_in,
                              void* d_out, int out_size, void* d_ws, size_t ws_size,
                              hipStream_t stream) {
    (void)in_sizes; (void)n_in; (void)out_size; (void)ws_size;
    const float* x     = (const float*)d_in[0];
    const int*   ei    = (const int*)d_in[1];
    const int*   batch = (const int*)d_in[2];
    const float* W1    = (const float*)d_in[3];
    const float* as1   = (const float*)d_in[4];
    const float* ad1   = (const float*)d_in[5];
    const float* b1    = (const float*)d_in[6];
    const float* W2    = (const float*)d_in[7];
    const float* as2   = (const float*)d_in[8];
    const float* ad2   = (const float*)d_in[9];
    const float* b2    = (const float*)d_in[10];
    const float* Wg    = (const float*)d_in[11];
    const float* bg    = (const float*)d_in[12];
    float* out = (float*)d_out;

    // ---- workspace layout (16-B aligned chunks; total ~35 MB) ----
    const long N = N_NODES;
    char* p = (char*)d_ws;
    int* rowptr = (int*)p;              p += (N + 4)        * sizeof(int);
    int* bcur   = (int*)p;              p += 1024           * sizeof(int);
    int* ecol   = (int*)p;              p += (long)ET       * sizeof(int);
    unsigned* gbuf = (unsigned*)p;      p += (long)NBUCK * BCAP * sizeof(unsigned);
    unsigned short* h1p  = (unsigned short*)p; p += N * 64  * sizeof(unsigned short);
    unsigned short* a1sh = (unsigned short*)p; p += N * 8   * sizeof(unsigned short);
    float* a1d  = (float*)p;            p += N * 8          * sizeof(float);
    float2* sg2 = (float2*)p;           p += N              * sizeof(float2);
    float* a2dv = (float*)p;            p += N              * sizeof(float);
    float* wv   = (float*)p;            p += 256            * sizeof(float);

    hipMemsetAsync(bcur, 0, NBUCK * sizeof(int), stream);
    // L1: CSR pass A + wv/out-init + conv1 features (co-scheduled)
    k_pre <<<PRE_GRID, 256, 0, stream>>>(ei, gbuf, bcur, x, W1, as1, ad1,
                                         W2, as2, ad2, Wg, b2, bg,
                                         h1p, a1sh, a1d, wv, out);
    // L2: fused build + conv1 gather + grid.sync + conv2/pool (cooperative)
    {
        const unsigned* gbuf_c = gbuf; const int* bcur_c = bcur;
        const unsigned short* a1sh_c = a1sh; const float* a1d_c = a1d;
        const unsigned short* h1p_c = h1p; const float* b1_c = b1;
        const float* wv_c = wv; float2* sg2_p = sg2; float* a2dv_p = a2dv;
        const int* batch_c = batch; float* out_p = out;
        void* args[] = { (void*)&gbuf_c, (void*)&bcur_c, (void*)&a1sh_c,
                         (void*)&a1d_c, (void*)&h1p_c, (void*)&b1_c,
                         (void*)&wv_c, (void*)&sg2_p, (void*)&a2dv_p,
                         (void*)&batch_c, (void*)&out_p };
        hipError_t err = hipLaunchCooperativeKernel(
            (const void*)k_gat12, dim3(NBUCK), dim3(512), args, 0, stream);
        if (err != hipSuccess) {
            // fallback: proven two-kernel path (r2/r6 behavior)
            k_gat1<<<NBUCK, 512, 0, stream>>>(gbuf, bcur, rowptr, ecol,
                                              a1sh, a1d, h1p, b1, wv, sg2, a2dv);
            k_gat2<<<G2_BLOCKS, 256, 0, stream>>>(rowptr, ecol, sg2, a2dv, wv,
                                                  batch, out);
        }
    }
}

// Round 9
// 339.930 us; speedup vs baseline: 2.4161x; 2.4161x over previous
//
#include <hip/hip_runtime.h>
#include <hip/hip_bf16.h>
#include <math.h>

#define N_NODES 100000
#define N_EDGES 1600000
#define ET (N_EDGES + N_NODES)   // edges + self-loops
#define N_GRAPHS 512
#define NEG_SLOPE 0.2f
#define G2_BLOCKS 1280           // persistent k_gat2 grid

// ---- bucketed CSR params ----
#define BSH 7                                 // 128 nodes per bucket
#define NDB 128                               // dsts per bucket
#define NBUCK ((N_NODES + NDB - 1) / NDB)     // 782
#define BCAP 2560                             // bucket capacity (mean 2174, +8 sigma)
#define ABLK 512                              // binA sub-grid
#define CHUNK ((ET + ABLK - 1) / ABLK)        // 3321 edges per binA block
#define F1_OFF (ABLK + 3)                     // feat1 blocks start here in k_pre
#define PRE_GRID (F1_OFF + 1536)              // 2051
#define SRC_MASK 131071u                      // low 17 bits = src id
#define DONE_SLOT 1023                        // done-counter index inside bcur[]

// binA LDS: pairs (CHUNK*4) + hist/gbase/cnt2 (NBUCK each) + excl (NBUCK+1) + red (256)
#define BINA_SMEM (CHUNK * 4 + NBUCK * 4 * 4 + 4 + 1024)   // 26824 B

__device__ __forceinline__ void atomAddF(float* p, float v) { unsafeAtomicAdd(p, v); }
__device__ __forceinline__ float lrelu(float v) { return v >= 0.f ? v : NEG_SLOPE * v; }

__device__ __forceinline__ unsigned short f2bf(float f) {
    unsigned int u = __float_as_uint(f);
    u += 0x7FFFu + ((u >> 16) & 1u);
    return (unsigned short)(u >> 16);
}
__device__ __forceinline__ float bf2f(unsigned short s) { return __uint_as_float(((unsigned int)s) << 16); }
__device__ __forceinline__ float bflo(unsigned int p) { return __uint_as_float(p << 16); }
__device__ __forceinline__ float bfhi(unsigned int p) { return __uint_as_float(p & 0xFFFF0000u); }

// ============ Launch 1: binA (blocks 0..ABLK-1) + wv/init + feat1 =========
__global__ __launch_bounds__(256) void k_pre(
    const int* __restrict__ ei, unsigned* __restrict__ gbuf, int* __restrict__ bcur,
    int* __restrict__ bbase,
    const float* __restrict__ x, const float* __restrict__ W1,
    const float* __restrict__ as1, const float* __restrict__ ad1,
    const float* __restrict__ W2, const float* __restrict__ as2,
    const float* __restrict__ ad2, const float* __restrict__ Wg,
    const float* __restrict__ b2, const float* __restrict__ bg,
    unsigned short* __restrict__ h1p, unsigned short* __restrict__ a1sh,
    float* __restrict__ a1d, float* __restrict__ wv, float* __restrict__ out)
{
    __shared__ __align__(16) char smem[BINA_SMEM];
    const int t = threadIdx.x;
    const int blk = blockIdx.x;

    if (blk >= ABLK && blk < F1_OFF) {
        // ---- misc: wv precompute / out init ----
        const int bb = blk - ABLK;
        if (bb == 0) {
            if (t < 192) {
                int c = t & 63, which = t >> 6;
                const float* v = (which == 0) ? Wg : ((which == 1) ? as2 : ad2);
                float s = 0.f;
                #pragma unroll
                for (int k = 0; k < 128; ++k) s += W2[c * 128 + k] * v[k];
                wv[which * 64 + c] = s;
            } else if (t == 192) {
                float s = 0.f;
                #pragma unroll
                for (int k = 0; k < 128; ++k) s += b2[k] * Wg[k];
                wv[192] = s;
            }
        } else {
            int i = (bb - 1) * 256 + t;
            if (i < N_GRAPHS) out[i] = bg[0];
        }
        return;
    }

    if (blk >= F1_OFF) {
        // ---- feat1 (persistent over node groups; original VGPR-52 form) ----
        float (*xs)[76] = (float (*)[76])smem;
        const int g = t >> 6;
        const int c = t & 63;
        const int vb = blk - F1_OFF;
        const int fstride = PRE_GRID - F1_OFF;
        for (int nb = vb; nb < N_NODES / 4; nb += fstride) {
            const int n = nb * 4 + g;
            const float* xr = x + (long)n * 75;
            xs[g][c] = xr[c];
            if (c < 11) xs[g][64 + c] = xr[64 + c];
            __syncthreads();
            float h = 0.f;
            #pragma unroll
            for (int k = 0; k < 75; ++k) h += xs[g][k] * W1[k * 64 + c];
            h1p[(long)n * 64 + c] = f2bf(h);
            const int head = c >> 3, lane = c & 7;
            float vs = h * as1[c];
            float vd = h * ad1[c];
            #pragma unroll
            for (int off = 1; off < 8; off <<= 1) {
                vs += __shfl_xor(vs, off, 64);
                vd += __shfl_xor(vd, off, 64);
            }
            if (lane == 0) { a1sh[n * 8 + head] = f2bf(vs); a1d[n * 8 + head] = vd; }
            __syncthreads();
        }
        return;
    }

    // ---- binA: per-chunk LDS counting sort by bucket (packed 4-B entries) ----
    unsigned* pairs = (unsigned*)smem;                 // CHUNK x 4 B: (dl<<17)|src
    int* hist  = (int*)(smem + CHUNK * 4);             // NBUCK
    int* excl  = hist + NBUCK;                         // NBUCK + 1
    int* gbase = excl + NBUCK + 1;                     // NBUCK
    int* cnt2  = gbase + NBUCK;                        // NBUCK
    int* red   = cnt2 + NBUCK;                         // 256
    const long e0 = (long)blk * CHUNK;
    const int  n  = (int)((e0 + CHUNK <= ET) ? CHUNK : (ET - e0));
    for (int i = t; i < NBUCK; i += 256) { hist[i] = 0; cnt2[i] = 0; }
    __syncthreads();
    for (int i = t; i < n; i += 256) {
        long e = e0 + i;
        int dst = (e < N_EDGES) ? ei[N_EDGES + e] : (int)(e - N_EDGES);
        atomicAdd(&hist[dst >> BSH], 1);
    }
    __syncthreads();
    // two-level parallel exclusive scan of hist[NBUCK] (4 buckets/thread)
    {
        int lk[4]; int s = 0;
        #pragma unroll
        for (int k = 0; k < 4; ++k) {
            int idx = t * 4 + k;
            int v = (idx < NBUCK) ? hist[idx] : 0;
            lk[k] = s; s += v;
        }
        red[t] = s;
        __syncthreads();
        for (int off = 1; off < 256; off <<= 1) {
            int a = (t >= off) ? red[t - off] : 0;
            __syncthreads();
            red[t] += a;
            __syncthreads();
        }
        int p = red[t] - s;   // exclusive prefix of this thread's chunk
        #pragma unroll
        for (int k = 0; k < 4; ++k) {
            int idx = t * 4 + k;
            if (idx < NBUCK) excl[idx] = p + lk[k];
        }
    }
    if (t == 0) excl[NBUCK] = n;
    __syncthreads();
    for (int i = t; i < n; i += 256) {
        long e = e0 + i;
        int src, dst;
        if (e < N_EDGES) { src = ei[e]; dst = ei[N_EDGES + e]; }
        else             { src = dst = (int)(e - N_EDGES); }
        int b = dst >> BSH;
        int pos = excl[b] + atomicAdd(&cnt2[b], 1);
        pairs[pos] = ((unsigned)(dst & (NDB - 1)) << 17) | (unsigned)src;
    }
    __syncthreads();
    for (int b = t; b < NBUCK; b += 256)
        gbase[b] = hist[b] ? atomicAdd(&bcur[b], hist[b]) : 0;
    __syncthreads();
    // flush: bucket-per-thread run copies
    for (int b = t; b < NBUCK; b += 256) {
        const int s = excl[b], e2 = excl[b + 1];
        if (s == e2) continue;
        unsigned* gp = gbuf + (long)b * BCAP + gbase[b];
        for (int i = s; i < e2; ++i) gp[i - s] = pairs[i];
    }

    // ---- last binA block: exclusive scan of bcur[] -> bbase[] -------------
    // (all blocks' bcur atomicAdds precede their done-increment, so the last
    //  block sees final counts; removes the per-block prefix phase in k_gat1)
    __threadfence();
    __syncthreads();
    if (t == 0) red[0] = (atomicAdd(&bcur[DONE_SLOT], 1) == ABLK - 1) ? 1 : 0;
    __syncthreads();
    const int amlast = red[0];
    __syncthreads();
    if (!amlast) return;
    {
        int lk[4]; int s = 0;
        #pragma unroll
        for (int k = 0; k < 4; ++k) {
            int idx = t * 4 + k;
            int v = (idx < NBUCK) ? bcur[idx] : 0;
            lk[k] = s; s += v;
        }
        red[t] = s;
        __syncthreads();
        for (int off = 1; off < 256; off <<= 1) {
            int a = (t >= off) ? red[t - off] : 0;
            __syncthreads();
            red[t] += a;
            __syncthreads();
        }
        int p = red[t] - s;
        #pragma unroll
        for (int k = 0; k < 4; ++k) {
            int idx = t * 4 + k;
            if (idx < NBUCK) bbase[idx] = p + lk[k];
        }
    }
}

// ---- shared gather macros (3-deep pipeline) ------------------------------
#define SLOT_INIT(k) \
    bool v##k = (k < dgl); \
    int s##k = v##k ? lds_src[beg + k] : 0; \
    unsigned short ab##k = a1sh[(long)s##k * 8 + l]; \
    uint4 pv##k = *(const uint4*)(h1p + (long)s##k * 64 + l * 8);

#define SLOT_STEP(k) { \
    float ee = v##k ? __expf(lrelu(bf2f(ab##k) + adh)) : 0.f; \
    den += ee; \
    acc[0] += ee * bflo(pv##k.x); acc[1] += ee * bfhi(pv##k.x); \
    acc[2] += ee * bflo(pv##k.y); acc[3] += ee * bfhi(pv##k.y); \
    acc[4] += ee * bflo(pv##k.z); acc[5] += ee * bfhi(pv##k.z); \
    acc[6] += ee * bflo(pv##k.w); acc[7] += ee * bfhi(pv##k.w); \
    v##k = (j + 3 + k) < dgl; \
    int sn = v##k ? lds_src[beg + j + 3 + k] : 0; \
    ab##k = a1sh[(long)sn * 8 + l]; \
    pv##k = *(const uint4*)(h1p + (long)sn * 64 + l * 8); }

// ====== Launch 2: binB build + gather (8-lane group = one dst) ============
__global__ __launch_bounds__(512) void k_gat1(
    const unsigned* __restrict__ gbuf, const int* __restrict__ bcur,
    const int* __restrict__ bbase,
    int* __restrict__ rowptr, int* __restrict__ ecol,
    const unsigned short* __restrict__ a1sh, const float* __restrict__ a1d,
    const unsigned short* __restrict__ h1p, const float* __restrict__ bias1,
    const float* __restrict__ wv,
    float2* __restrict__ sg2, float* __restrict__ a2dv)
{
    __shared__ int lds_src[BCAP];
    __shared__ int hist[NDB], excl[NDB + 1], cnt2[NDB];
    __shared__ int red[512];
    const int t = threadIdx.x;
    const int b = blockIdx.x;
    const int d0 = b << BSH;
    const int nloc = (N_NODES - d0 < NDB) ? (N_NODES - d0) : NDB;
    int cntr = bcur[b];
    const int cnt = cntr < BCAP ? cntr : BCAP;
    const int base = bbase[b];              // precomputed in k_pre's last block

    // ---- local histogram over 128 dsts ----
    if (t < NDB) { hist[t] = 0; cnt2[t] = 0; }
    __syncthreads();
    const unsigned* eb = gbuf + (long)b * BCAP;
    for (int i = t; i < cnt; i += 512) atomicAdd(&hist[eb[i] >> 17], 1);
    __syncthreads();
    // ---- parallel exclusive scan of hist[128] ----
    {
        int v = (t < NDB) ? hist[t] : 0;
        if (t < NDB) red[t] = v;
        __syncthreads();
        for (int off = 1; off < NDB; off <<= 1) {
            int a = (t < NDB && t >= off) ? red[t - off] : 0;
            __syncthreads();
            if (t < NDB) red[t] += a;
            __syncthreads();
        }
        if (t < nloc) excl[t] = red[t] - v;
        if (t == 0) excl[nloc] = cnt;
    }
    __syncthreads();
    // ---- rowptr + LDS scatter (src only) + ecol flush (for gat2) ----
    if (t < nloc) rowptr[d0 + t] = base + excl[t];
    if (b == NBUCK - 1 && t == 0) rowptr[N_NODES] = base + cnt;
    for (int i = t; i < cnt; i += 512) {
        unsigned pr = eb[i];
        int dl = (int)(pr >> 17);
        int slot = excl[dl] + atomicAdd(&cnt2[dl], 1);
        lds_src[slot] = (int)(pr & SRC_MASK);
    }
    __syncthreads();
    for (int i = t; i < cnt; i += 512) ecol[base + i] = lds_src[i];

    // ---- gather: lane l = head l (owns 8 ch); 3-deep pipeline; edges in LDS.
    //      den/acc head-local -> no cross-group reduction per dst. ----
    const int l = t & 7;
    const int gid = t >> 3;                  // 0..63 groups
    for (int dl = gid; dl < nloc; dl += 64) {
        const int dst = d0 + dl;
        const int beg = excl[dl];
        const int dgl = excl[dl + 1] - beg;  // >= 1 (self-loop)
        const float adh = a1d[(long)dst * 8 + l];

        float acc[8] = {0.f,0.f,0.f,0.f,0.f,0.f,0.f,0.f};
        float den = 0.f;

        SLOT_INIT(0) SLOT_INIT(1) SLOT_INIT(2)

        for (int j = 0; j < dgl; j += 3) {
            SLOT_STEP(0) SLOT_STEP(1) SLOT_STEP(2)
        }

        // ---- epilogue: normalize, bias, ELU, project to (pg, ps, pd) ----
        const float inv = 1.f / den;
        float pg = 0.f, ps = 0.f, pd = 0.f;
        #pragma unroll
        for (int k = 0; k < 8; ++k) {
            float vv = acc[k] * inv + bias1[l * 8 + k];
            vv = vv > 0.f ? vv : (__expf(vv) - 1.f);      // elu -> x2 channel
            pg += vv * wv[l * 8 + k];
            ps += vv * wv[64 + l * 8 + k];
            pd += vv * wv[128 + l * 8 + k];
        }
        #pragma unroll
        for (int off = 1; off < 8; off <<= 1) {           // reduce over 8 head-lanes
            pg += __shfl_xor(pg, off, 64);
            ps += __shfl_xor(ps, off, 64);
            pd += __shfl_xor(pd, off, 64);
        }
        if (l == 0) { sg2[dst] = make_float2(ps, pg); a2dv[dst] = pd; }
    }
}

// ---- conv2 + pool + linear (persistent, 16-lane subgroups; r2-exact) -----
__global__ __launch_bounds__(256) void k_gat2(
    const int* __restrict__ rowptr, const int* __restrict__ ecol,
    const float2* __restrict__ sg2, const float* __restrict__ a2dv,
    const float* __restrict__ wv, const int* __restrict__ batch,
    float* __restrict__ out)
{
    const int sl = threadIdx.x & 15;
    const int sgid = ((blockIdx.x * 256 + threadIdx.x) >> 4);
    const int NS = G2_BLOCKS * 16;
    const int per = (N_NODES + NS - 1) / NS;
    const int n0 = sgid * per;
    const int n1 = min(n0 + per, N_NODES);
    const float bc = wv[192];

    float accg = 0.f;
    int curg = -1;
    for (int n = n0; n < n1; ++n) {
        const int beg = rowptr[n], end = rowptr[n + 1];
        const float adv = a2dv[n];
        float num = 0.f, den = 0.f;
        for (int j = beg + sl; j < end; j += 16) {
            int s = ecol[j];
            float2 v = sg2[s];
            float ee = __expf(lrelu(v.x + adv));
            den += ee;
            num += ee * v.y;
        }
        #pragma unroll
        for (int off = 1; off < 16; off <<= 1) {
            den += __shfl_xor(den, off, 64);
            num += __shfl_xor(num, off, 64);
        }
        if (sl == 0) {
            int gr = batch[n];
            if (gr != curg) {
                if (curg >= 0) atomAddF(out + curg, accg);
                curg = gr; accg = 0.f;
            }
            accg += num / den + bc;
        }
    }
    if (sl == 0 && curg >= 0) atomAddF(out + curg, accg);
}

extern "C" void kernel_launch(void* const* d_in, const int* in_sizes, int n_in,
                              void* d_out, int out_size, void* d_ws, size_t ws_size,
                              hipStream_t stream) {
    (void)in_sizes; (void)n_in; (void)out_size; (void)ws_size;
    const float* x     = (const float*)d_in[0];
    const int*   ei    = (const int*)d_in[1];
    const int*   batch = (const int*)d_in[2];
    const float* W1    = (const float*)d_in[3];
    const float* as1   = (const float*)d_in[4];
    const float* ad1   = (const float*)d_in[5];
    const float* b1    = (const float*)d_in[6];
    const float* W2    = (const float*)d_in[7];
    const float* as2   = (const float*)d_in[8];
    const float* ad2   = (const float*)d_in[9];
    const float* b2    = (const float*)d_in[10];
    const float* Wg    = (const float*)d_in[11];
    const float* bg    = (const float*)d_in[12];
    float* out = (float*)d_out;

    // ---- workspace layout (16-B aligned chunks; total ~35 MB) ----
    const long N = N_NODES;
    char* p = (char*)d_ws;
    int* rowptr = (int*)p;              p += (N + 4)        * sizeof(int);
    int* bcur   = (int*)p;              p += 1024           * sizeof(int);
    int* bbase  = (int*)p;              p += 1024           * sizeof(int);
    int* ecol   = (int*)p;              p += (long)ET       * sizeof(int);
    unsigned* gbuf = (unsigned*)p;      p += (long)NBUCK * BCAP * sizeof(unsigned);
    unsigned short* h1p  = (unsigned short*)p; p += N * 64  * sizeof(unsigned short);
    unsigned short* a1sh = (unsigned short*)p; p += N * 8   * sizeof(unsigned short);
    float* a1d  = (float*)p;            p += N * 8          * sizeof(float);
    float2* sg2 = (float2*)p;           p += N              * sizeof(float2);
    float* a2dv = (float*)p;            p += N              * sizeof(float);
    float* wv   = (float*)p;            p += 256            * sizeof(float);

    hipMemsetAsync(bcur, 0, 1024 * sizeof(int), stream);   // counters + done slot
    // L1: CSR pass A + wv/out-init + conv1 features (co-scheduled);
    //     last binA block publishes bbase[] (exclusive scan of bcur)
    k_pre <<<PRE_GRID, 256, 0, stream>>>(ei, gbuf, bcur, bbase, x, W1, as1, ad1,
                                         W2, as2, ad2, Wg, b2, bg,
                                         h1p, a1sh, a1d, wv, out);
    // L2: CSR pass B + conv1 gather + projection (8-lane group per dst)
    k_gat1<<<NBUCK, 512, 0, stream>>>(gbuf, bcur, bbase, rowptr, ecol,
                                      a1sh, a1d, h1p, b1, wv, sg2, a2dv);
    // L3: conv2 + pool + linear
    k_gat2<<<G2_BLOCKS, 256, 0, stream>>>(rowptr, ecol, sg2, a2dv, wv, batch, out);
}

// Round 10
// 264.522 us; speedup vs baseline: 3.1049x; 1.2851x over previous
//
#include <hip/hip_runtime.h>
#include <hip/hip_bf16.h>
#include <math.h>

#define N_NODES 100000
#define N_EDGES 1600000
#define ET (N_EDGES + N_NODES)   // edges + self-loops
#define N_GRAPHS 512
#define NEG_SLOPE 0.2f
#define G2_BLOCKS 1280           // persistent k_gat2 grid

// ---- bucketed CSR params ----
#define BSH 7                                 // 128 nodes per bucket
#define NDB 128                               // dsts per bucket
#define NBUCK ((N_NODES + NDB - 1) / NDB)     // 782
#define BCAP 2560                             // bucket capacity (mean 2174, +8 sigma)
#define ABLK 512                              // binA sub-grid
#define CHUNK ((ET + ABLK - 1) / ABLK)        // 3321 edges per binA block
#define F1_OFF (ABLK + 3)                     // feat1 blocks start here in k_pre
#define PRE_GRID (F1_OFF + 1536)              // 2051
#define SRC_MASK 131071u                      // low 17 bits = src id

// binA LDS: pairs (CHUNK*4) + hist/gbase/cnt2 (NBUCK each) + excl (NBUCK+1) + red (256)
#define BINA_SMEM (CHUNK * 4 + NBUCK * 4 * 4 + 4 + 1024)   // 26824 B

__device__ __forceinline__ void atomAddF(float* p, float v) { unsafeAtomicAdd(p, v); }
__device__ __forceinline__ float lrelu(float v) { return v >= 0.f ? v : NEG_SLOPE * v; }

__device__ __forceinline__ unsigned short f2bf(float f) {
    unsigned int u = __float_as_uint(f);
    u += 0x7FFFu + ((u >> 16) & 1u);
    return (unsigned short)(u >> 16);
}
__device__ __forceinline__ float bf2f(unsigned short s) { return __uint_as_float(((unsigned int)s) << 16); }
__device__ __forceinline__ float bflo(unsigned int p) { return __uint_as_float(p << 16); }
__device__ __forceinline__ float bfhi(unsigned int p) { return __uint_as_float(p & 0xFFFF0000u); }

// ============ Launch 1: binA (blocks 0..ABLK-1) + wv/init + feat1 =========
// (r6-exact: no threadfence, no bbase tail — measured 75.5 us)
__global__ __launch_bounds__(256) void k_pre(
    const int* __restrict__ ei, unsigned* __restrict__ gbuf, int* __restrict__ bcur,
    const float* __restrict__ x, const float* __restrict__ W1,
    const float* __restrict__ as1, const float* __restrict__ ad1,
    const float* __restrict__ W2, const float* __restrict__ as2,
    const float* __restrict__ ad2, const float* __restrict__ Wg,
    const float* __restrict__ b2, const float* __restrict__ bg,
    unsigned short* __restrict__ h1p, unsigned short* __restrict__ a1sh,
    float* __restrict__ a1d, float* __restrict__ wv, float* __restrict__ out)
{
    __shared__ __align__(16) char smem[BINA_SMEM];
    const int t = threadIdx.x;
    const int blk = blockIdx.x;

    if (blk >= ABLK && blk < F1_OFF) {
        // ---- misc: wv precompute / out init ----
        const int bb = blk - ABLK;
        if (bb == 0) {
            if (t < 192) {
                int c = t & 63, which = t >> 6;
                const float* v = (which == 0) ? Wg : ((which == 1) ? as2 : ad2);
                float s = 0.f;
                #pragma unroll
                for (int k = 0; k < 128; ++k) s += W2[c * 128 + k] * v[k];
                wv[which * 64 + c] = s;
            } else if (t == 192) {
                float s = 0.f;
                #pragma unroll
                for (int k = 0; k < 128; ++k) s += b2[k] * Wg[k];
                wv[192] = s;
            }
        } else {
            int i = (bb - 1) * 256 + t;
            if (i < N_GRAPHS) out[i] = bg[0];
        }
        return;
    }

    if (blk >= F1_OFF) {
        // ---- feat1 (persistent over node groups; original VGPR-52 form) ----
        float (*xs)[76] = (float (*)[76])smem;
        const int g = t >> 6;
        const int c = t & 63;
        const int vb = blk - F1_OFF;
        const int fstride = PRE_GRID - F1_OFF;
        for (int nb = vb; nb < N_NODES / 4; nb += fstride) {
            const int n = nb * 4 + g;
            const float* xr = x + (long)n * 75;
            xs[g][c] = xr[c];
            if (c < 11) xs[g][64 + c] = xr[64 + c];
            __syncthreads();
            float h = 0.f;
            #pragma unroll
            for (int k = 0; k < 75; ++k) h += xs[g][k] * W1[k * 64 + c];
            h1p[(long)n * 64 + c] = f2bf(h);
            const int head = c >> 3, lane = c & 7;
            float vs = h * as1[c];
            float vd = h * ad1[c];
            #pragma unroll
            for (int off = 1; off < 8; off <<= 1) {
                vs += __shfl_xor(vs, off, 64);
                vd += __shfl_xor(vd, off, 64);
            }
            if (lane == 0) { a1sh[n * 8 + head] = f2bf(vs); a1d[n * 8 + head] = vd; }
            __syncthreads();
        }
        return;
    }

    // ---- binA: per-chunk LDS counting sort by bucket (packed 4-B entries) ----
    unsigned* pairs = (unsigned*)smem;                 // CHUNK x 4 B: (dl<<17)|src
    int* hist  = (int*)(smem + CHUNK * 4);             // NBUCK
    int* excl  = hist + NBUCK;                         // NBUCK + 1
    int* gbase = excl + NBUCK + 1;                     // NBUCK
    int* cnt2  = gbase + NBUCK;                        // NBUCK
    int* red   = cnt2 + NBUCK;                         // 256
    const long e0 = (long)blk * CHUNK;
    const int  n  = (int)((e0 + CHUNK <= ET) ? CHUNK : (ET - e0));
    for (int i = t; i < NBUCK; i += 256) { hist[i] = 0; cnt2[i] = 0; }
    __syncthreads();
    for (int i = t; i < n; i += 256) {
        long e = e0 + i;
        int dst = (e < N_EDGES) ? ei[N_EDGES + e] : (int)(e - N_EDGES);
        atomicAdd(&hist[dst >> BSH], 1);
    }
    __syncthreads();
    // two-level parallel exclusive scan of hist[NBUCK] (4 buckets/thread)
    {
        int lk[4]; int s = 0;
        #pragma unroll
        for (int k = 0; k < 4; ++k) {
            int idx = t * 4 + k;
            int v = (idx < NBUCK) ? hist[idx] : 0;
            lk[k] = s; s += v;
        }
        red[t] = s;
        __syncthreads();
        for (int off = 1; off < 256; off <<= 1) {
            int a = (t >= off) ? red[t - off] : 0;
            __syncthreads();
            red[t] += a;
            __syncthreads();
        }
        int p = red[t] - s;   // exclusive prefix of this thread's chunk
        #pragma unroll
        for (int k = 0; k < 4; ++k) {
            int idx = t * 4 + k;
            if (idx < NBUCK) excl[idx] = p + lk[k];
        }
    }
    if (t == 0) excl[NBUCK] = n;
    __syncthreads();
    for (int i = t; i < n; i += 256) {
        long e = e0 + i;
        int src, dst;
        if (e < N_EDGES) { src = ei[e]; dst = ei[N_EDGES + e]; }
        else             { src = dst = (int)(e - N_EDGES); }
        int b = dst >> BSH;
        int pos = excl[b] + atomicAdd(&cnt2[b], 1);
        pairs[pos] = ((unsigned)(dst & (NDB - 1)) << 17) | (unsigned)src;
    }
    __syncthreads();
    for (int b = t; b < NBUCK; b += 256)
        gbase[b] = hist[b] ? atomicAdd(&bcur[b], hist[b]) : 0;
    __syncthreads();
    // flush: bucket-per-thread run copies
    for (int b = t; b < NBUCK; b += 256) {
        const int s = excl[b], e2 = excl[b + 1];
        if (s == e2) continue;
        unsigned* gp = gbuf + (long)b * BCAP + gbase[b];
        for (int i = s; i < e2; ++i) gp[i - s] = pairs[i];
    }
}

// ====== Launch 2: binB build only -> rowptr + ecol ========================
// r6 k_gat1's build phase verbatim (prefix reduce + hist/scan + LDS scatter
// + coalesced ecol flush); gather moved to its own high-occupancy kernel.
__global__ __launch_bounds__(512) void k_build(
    const unsigned* __restrict__ gbuf, const int* __restrict__ bcur,
    int* __restrict__ rowptr, int* __restrict__ ecol)
{
    __shared__ int lds_src[BCAP];
    __shared__ int hist[NDB], excl[NDB + 1], cnt2[NDB];
    __shared__ int red[512];
    const int t = threadIdx.x;
    const int b = blockIdx.x;
    const int d0 = b << BSH;
    const int nloc = (N_NODES - d0 < NDB) ? (N_NODES - d0) : NDB;
    int cntr = bcur[b];
    const int cnt = cntr < BCAP ? cntr : BCAP;

    // ---- base = sum of bcur[0..b) (tree reduce over strided partials) ----
    int partial = 0;
    for (int i = t; i < b; i += 512) partial += bcur[i];
    red[t] = partial;
    __syncthreads();
    for (int off = 256; off > 0; off >>= 1) {
        if (t < off) red[t] += red[t + off];
        __syncthreads();
    }
    const int base = red[0];
    __syncthreads();

    // ---- local histogram over 128 dsts ----
    if (t < NDB) { hist[t] = 0; cnt2[t] = 0; }
    __syncthreads();
    const unsigned* eb = gbuf + (long)b * BCAP;
    for (int i = t; i < cnt; i += 512) atomicAdd(&hist[eb[i] >> 17], 1);
    __syncthreads();
    // ---- parallel exclusive scan of hist[128] ----
    {
        int v = (t < NDB) ? hist[t] : 0;
        if (t < NDB) red[t] = v;
        __syncthreads();
        for (int off = 1; off < NDB; off <<= 1) {
            int a = (t < NDB && t >= off) ? red[t - off] : 0;
            __syncthreads();
            if (t < NDB) red[t] += a;
            __syncthreads();
        }
        if (t < nloc) excl[t] = red[t] - v;
        if (t == 0) excl[nloc] = cnt;
    }
    __syncthreads();
    if (t < nloc) rowptr[d0 + t] = base + excl[t];
    if (b == NBUCK - 1 && t == 0) rowptr[N_NODES] = base + cnt;
    for (int i = t; i < cnt; i += 512) {
        unsigned pr = eb[i];
        int dl = (int)(pr >> 17);
        int slot = excl[dl] + atomicAdd(&cnt2[dl], 1);
        lds_src[slot] = (int)(pr & SRC_MASK);
    }
    __syncthreads();
    for (int i = t; i < cnt; i += 512) ecol[base + i] = lds_src[i];
}

// ====== Launch 3: gather-only conv1 (8-lane group = one dst, no LDS) ======
// Barrier-free, 3125x256, plain launch_bounds (r4's (256,6) cap removed).
#define GSLOT_INIT(k) \
    bool v##k = (k < dgl); \
    int s##k = v##k ? erow[k] : 0; \
    unsigned short ab##k = a1sh[(long)s##k * 8 + l]; \
    uint4 pv##k = *(const uint4*)(h1p + (long)s##k * 64 + l * 8);

#define GSLOT_STEP(k) { \
    float ee = v##k ? __expf(lrelu(bf2f(ab##k) + adh)) : 0.f; \
    den += ee; \
    acc[0] += ee * bflo(pv##k.x); acc[1] += ee * bfhi(pv##k.x); \
    acc[2] += ee * bflo(pv##k.y); acc[3] += ee * bfhi(pv##k.y); \
    acc[4] += ee * bflo(pv##k.z); acc[5] += ee * bfhi(pv##k.z); \
    acc[6] += ee * bflo(pv##k.w); acc[7] += ee * bfhi(pv##k.w); \
    v##k = (j + 3 + k) < dgl; \
    int sn = v##k ? erow[j + 3 + k] : 0; \
    ab##k = a1sh[(long)sn * 8 + l]; \
    pv##k = *(const uint4*)(h1p + (long)sn * 64 + l * 8); }

__global__ __launch_bounds__(256) void k_gath(
    const int* __restrict__ rowptr, const int* __restrict__ ecol,
    const unsigned short* __restrict__ a1sh, const float* __restrict__ a1d,
    const unsigned short* __restrict__ h1p, const float* __restrict__ bias1,
    const float* __restrict__ wv,
    float2* __restrict__ sg2, float* __restrict__ a2dv)
{
    const int t = threadIdx.x;
    const int l = t & 7;
    const int dst = (blockIdx.x * 256 + t) >> 3;   // grid covers exactly N_NODES

    const int beg = rowptr[dst];
    const int dgl = rowptr[dst + 1] - beg;          // >= 1 (self-loop)
    const int* __restrict__ erow = ecol + beg;
    const float adh = a1d[(long)dst * 8 + l];

    float acc[8] = {0.f,0.f,0.f,0.f,0.f,0.f,0.f,0.f};
    float den = 0.f;

    GSLOT_INIT(0) GSLOT_INIT(1) GSLOT_INIT(2)
    for (int j = 0; j < dgl; j += 3) {
        GSLOT_STEP(0) GSLOT_STEP(1) GSLOT_STEP(2)
    }

    // epilogue: normalize, bias, ELU, project to (pg, ps, pd)
    const float inv = 1.f / den;
    float pg = 0.f, ps = 0.f, pd = 0.f;
    #pragma unroll
    for (int k = 0; k < 8; ++k) {
        float vv = acc[k] * inv + bias1[l * 8 + k];
        vv = vv > 0.f ? vv : (__expf(vv) - 1.f);      // elu -> x2 channel
        pg += vv * wv[l * 8 + k];
        ps += vv * wv[64 + l * 8 + k];
        pd += vv * wv[128 + l * 8 + k];
    }
    #pragma unroll
    for (int off = 1; off < 8; off <<= 1) {           // reduce over 8 head-lanes
        pg += __shfl_xor(pg, off, 64);
        ps += __shfl_xor(ps, off, 64);
        pd += __shfl_xor(pd, off, 64);
    }
    if (l == 0) { sg2[dst] = make_float2(ps, pg); a2dv[dst] = pd; }
}

// ---- conv2 + pool + linear (persistent, 16-lane subgroups; r2-exact) -----
__global__ __launch_bounds__(256) void k_gat2(
    const int* __restrict__ rowptr, const int* __restrict__ ecol,
    const float2* __restrict__ sg2, const float* __restrict__ a2dv,
    const float* __restrict__ wv, const int* __restrict__ batch,
    float* __restrict__ out)
{
    const int sl = threadIdx.x & 15;
    const int sgid = ((blockIdx.x * 256 + threadIdx.x) >> 4);
    const int NS = G2_BLOCKS * 16;
    const int per = (N_NODES + NS - 1) / NS;
    const int n0 = sgid * per;
    const int n1 = min(n0 + per, N_NODES);
    const float bc = wv[192];

    float accg = 0.f;
    int curg = -1;
    for (int n = n0; n < n1; ++n) {
        const int beg = rowptr[n], end = rowptr[n + 1];
        const float adv = a2dv[n];
        float num = 0.f, den = 0.f;
        for (int j = beg + sl; j < end; j += 16) {
            int s = ecol[j];
            float2 v = sg2[s];
            float ee = __expf(lrelu(v.x + adv));
            den += ee;
            num += ee * v.y;
        }
        #pragma unroll
        for (int off = 1; off < 16; off <<= 1) {
            den += __shfl_xor(den, off, 64);
            num += __shfl_xor(num, off, 64);
        }
        if (sl == 0) {
            int gr = batch[n];
            if (gr != curg) {
                if (curg >= 0) atomAddF(out + curg, accg);
                curg = gr; accg = 0.f;
            }
            accg += num / den + bc;
        }
    }
    if (sl == 0 && curg >= 0) atomAddF(out + curg, accg);
}

extern "C" void kernel_launch(void* const* d_in, const int* in_sizes, int n_in,
                              void* d_out, int out_size, void* d_ws, size_t ws_size,
                              hipStream_t stream) {
    (void)in_sizes; (void)n_in; (void)out_size; (void)ws_size;
    const float* x     = (const float*)d_in[0];
    const int*   ei    = (const int*)d_in[1];
    const int*   batch = (const int*)d_in[2];
    const float* W1    = (const float*)d_in[3];
    const float* as1   = (const float*)d_in[4];
    const float* ad1   = (const float*)d_in[5];
    const float* b1    = (const float*)d_in[6];
    const float* W2    = (const float*)d_in[7];
    const float* as2   = (const float*)d_in[8];
    const float* ad2   = (const float*)d_in[9];
    const float* b2    = (const float*)d_in[10];
    const float* Wg    = (const float*)d_in[11];
    const float* bg    = (const float*)d_in[12];
    float* out = (float*)d_out;

    // ---- workspace layout (16-B aligned chunks; total ~35 MB) ----
    const long N = N_NODES;
    char* p = (char*)d_ws;
    int* rowptr = (int*)p;              p += (N + 4)        * sizeof(int);
    int* bcur   = (int*)p;              p += 1024           * sizeof(int);
    int* ecol   = (int*)p;              p += (long)ET       * sizeof(int);
    unsigned* gbuf = (unsigned*)p;      p += (long)NBUCK * BCAP * sizeof(unsigned);
    unsigned short* h1p  = (unsigned short*)p; p += N * 64  * sizeof(unsigned short);
    unsigned short* a1sh = (unsigned short*)p; p += N * 8   * sizeof(unsigned short);
    float* a1d  = (float*)p;            p += N * 8          * sizeof(float);
    float2* sg2 = (float2*)p;           p += N              * sizeof(float2);
    float* a2dv = (float*)p;            p += N              * sizeof(float);
    float* wv   = (float*)p;            p += 256            * sizeof(float);

    hipMemsetAsync(bcur, 0, NBUCK * sizeof(int), stream);
    // L1: CSR pass A + wv/out-init + conv1 features (co-scheduled)
    k_pre <<<PRE_GRID, 256, 0, stream>>>(ei, gbuf, bcur, x, W1, as1, ad1,
                                         W2, as2, ad2, Wg, b2, bg,
                                         h1p, a1sh, a1d, wv, out);
    // L2: CSR pass B (rowptr + ecol only)
    k_build<<<NBUCK, 512, 0, stream>>>(gbuf, bcur, rowptr, ecol);
    // L3: conv1 gather + projection (barrier-free, high-occupancy)
    k_gath<<<N_NODES / 32, 256, 0, stream>>>(rowptr, ecol, a1sh, a1d, h1p, b1,
                                             wv, sg2, a2dv);
    // L4: conv2 + pool + linear
    k_gat2<<<G2_BLOCKS, 256, 0, stream>>>(rowptr, ecol, sg2, a2dv, wv, batch, out);
}

// Round 11
// 263.623 us; speedup vs baseline: 3.1155x; 1.0034x over previous
//
#include <hip/hip_runtime.h>
#include <hip/hip_bf16.h>
#include <math.h>

#define N_NODES 100000
#define N_EDGES 1600000
#define ET (N_EDGES + N_NODES)   // edges + self-loops
#define N_GRAPHS 512
#define NEG_SLOPE 0.2f
#define G2_BLOCKS 1280           // persistent k_gat2 grid (r2-exact)

// ---- bucketed CSR params ----
#define BSH 7                                 // 128 nodes per bucket
#define NDB 128                               // dsts per bucket
#define NBUCK ((N_NODES + NDB - 1) / NDB)     // 782
#define BCAP 2560                             // bucket capacity (mean 2174, +8 sigma)
#define ABLK 512                              // binA sub-grid
#define CHUNK ((ET + ABLK - 1) / ABLK)        // 3321 edges per binA block
#define F1_OFF (ABLK + 3)                     // feat1 blocks start here in k_pre
#define PRE_GRID (F1_OFF + 1536)              // 2051
#define SRC_MASK 131071u                      // low 17 bits = src id

// binA LDS: pairs (CHUNK*4) + hist/gbase/cnt2 (NBUCK each) + excl (NBUCK+1) + red (256)
#define BINA_SMEM (CHUNK * 4 + NBUCK * 4 * 4 + 4 + 1024)   // 26824 B

__device__ __forceinline__ void atomAddF(float* p, float v) { unsafeAtomicAdd(p, v); }
__device__ __forceinline__ float lrelu(float v) { return v >= 0.f ? v : NEG_SLOPE * v; }

__device__ __forceinline__ unsigned short f2bf(float f) {
    unsigned int u = __float_as_uint(f);
    u += 0x7FFFu + ((u >> 16) & 1u);
    return (unsigned short)(u >> 16);
}
__device__ __forceinline__ float bf2f(unsigned short s) { return __uint_as_float(((unsigned int)s) << 16); }
__device__ __forceinline__ float bflo(unsigned int p) { return __uint_as_float(p << 16); }
__device__ __forceinline__ float bfhi(unsigned int p) { return __uint_as_float(p & 0xFFFF0000u); }

// ============ Launch 1: binA (blocks 0..ABLK-1) + wv/init + feat1 =========
// (r6-exact: measured 74.4-80.6 us)
__global__ __launch_bounds__(256) void k_pre(
    const int* __restrict__ ei, unsigned* __restrict__ gbuf, int* __restrict__ bcur,
    const float* __restrict__ x, const float* __restrict__ W1,
    const float* __restrict__ as1, const float* __restrict__ ad1,
    const float* __restrict__ W2, const float* __restrict__ as2,
    const float* __restrict__ ad2, const float* __restrict__ Wg,
    const float* __restrict__ b2, const float* __restrict__ bg,
    unsigned short* __restrict__ h1p, unsigned short* __restrict__ a1sh,
    float* __restrict__ a1d, float* __restrict__ wv, float* __restrict__ out)
{
    __shared__ __align__(16) char smem[BINA_SMEM];
    const int t = threadIdx.x;
    const int blk = blockIdx.x;

    if (blk >= ABLK && blk < F1_OFF) {
        // ---- misc: wv precompute / out init ----
        const int bb = blk - ABLK;
        if (bb == 0) {
            if (t < 192) {
                int c = t & 63, which = t >> 6;
                const float* v = (which == 0) ? Wg : ((which == 1) ? as2 : ad2);
                float s = 0.f;
                #pragma unroll
                for (int k = 0; k < 128; ++k) s += W2[c * 128 + k] * v[k];
                wv[which * 64 + c] = s;
            } else if (t == 192) {
                float s = 0.f;
                #pragma unroll
                for (int k = 0; k < 128; ++k) s += b2[k] * Wg[k];
                wv[192] = s;
            }
        } else {
            int i = (bb - 1) * 256 + t;
            if (i < N_GRAPHS) out[i] = bg[0];
        }
        return;
    }

    if (blk >= F1_OFF) {
        // ---- feat1 (persistent over node groups; original VGPR-52 form) ----
        float (*xs)[76] = (float (*)[76])smem;
        const int g = t >> 6;
        const int c = t & 63;
        const int vb = blk - F1_OFF;
        const int fstride = PRE_GRID - F1_OFF;
        for (int nb = vb; nb < N_NODES / 4; nb += fstride) {
            const int n = nb * 4 + g;
            const float* xr = x + (long)n * 75;
            xs[g][c] = xr[c];
            if (c < 11) xs[g][64 + c] = xr[64 + c];
            __syncthreads();
            float h = 0.f;
            #pragma unroll
            for (int k = 0; k < 75; ++k) h += xs[g][k] * W1[k * 64 + c];
            h1p[(long)n * 64 + c] = f2bf(h);
            const int head = c >> 3, lane = c & 7;
            float vs = h * as1[c];
            float vd = h * ad1[c];
            #pragma unroll
            for (int off = 1; off < 8; off <<= 1) {
                vs += __shfl_xor(vs, off, 64);
                vd += __shfl_xor(vd, off, 64);
            }
            if (lane == 0) { a1sh[n * 8 + head] = f2bf(vs); a1d[n * 8 + head] = vd; }
            __syncthreads();
        }
        return;
    }

    // ---- binA: per-chunk LDS counting sort by bucket (packed 4-B entries) ----
    unsigned* pairs = (unsigned*)smem;                 // CHUNK x 4 B: (dl<<17)|src
    int* hist  = (int*)(smem + CHUNK * 4);             // NBUCK
    int* excl  = hist + NBUCK;                         // NBUCK + 1
    int* gbase = excl + NBUCK + 1;                     // NBUCK
    int* cnt2  = gbase + NBUCK;                        // NBUCK
    int* red   = cnt2 + NBUCK;                         // 256
    const long e0 = (long)blk * CHUNK;
    const int  n  = (int)((e0 + CHUNK <= ET) ? CHUNK : (ET - e0));
    for (int i = t; i < NBUCK; i += 256) { hist[i] = 0; cnt2[i] = 0; }
    __syncthreads();
    for (int i = t; i < n; i += 256) {
        long e = e0 + i;
        int dst = (e < N_EDGES) ? ei[N_EDGES + e] : (int)(e - N_EDGES);
        atomicAdd(&hist[dst >> BSH], 1);
    }
    __syncthreads();
    // two-level parallel exclusive scan of hist[NBUCK] (4 buckets/thread)
    {
        int lk[4]; int s = 0;
        #pragma unroll
        for (int k = 0; k < 4; ++k) {
            int idx = t * 4 + k;
            int v = (idx < NBUCK) ? hist[idx] : 0;
            lk[k] = s; s += v;
        }
        red[t] = s;
        __syncthreads();
        for (int off = 1; off < 256; off <<= 1) {
            int a = (t >= off) ? red[t - off] : 0;
            __syncthreads();
            red[t] += a;
            __syncthreads();
        }
        int p = red[t] - s;   // exclusive prefix of this thread's chunk
        #pragma unroll
        for (int k = 0; k < 4; ++k) {
            int idx = t * 4 + k;
            if (idx < NBUCK) excl[idx] = p + lk[k];
        }
    }
    if (t == 0) excl[NBUCK] = n;
    __syncthreads();
    for (int i = t; i < n; i += 256) {
        long e = e0 + i;
        int src, dst;
        if (e < N_EDGES) { src = ei[e]; dst = ei[N_EDGES + e]; }
        else             { src = dst = (int)(e - N_EDGES); }
        int b = dst >> BSH;
        int pos = excl[b] + atomicAdd(&cnt2[b], 1);
        pairs[pos] = ((unsigned)(dst & (NDB - 1)) << 17) | (unsigned)src;
    }
    __syncthreads();
    for (int b = t; b < NBUCK; b += 256)
        gbase[b] = hist[b] ? atomicAdd(&bcur[b], hist[b]) : 0;
    __syncthreads();
    // flush: bucket-per-thread run copies
    for (int b = t; b < NBUCK; b += 256) {
        const int s = excl[b], e2 = excl[b + 1];
        if (s == e2) continue;
        unsigned* gp = gbuf + (long)b * BCAP + gbase[b];
        for (int i = s; i < e2; ++i) gp[i - s] = pairs[i];
    }
}

// ====== Launch 2: binB build + gather (8-lane group = one dst) ============
// (r6-exact: measured 74.4-74.8 us)
#define SLOT_INIT(k) \
    bool v##k = (k < dgl); \
    int s##k = v##k ? lds_src[beg + k] : 0; \
    unsigned short ab##k = a1sh[(long)s##k * 8 + l]; \
    uint4 pv##k = *(const uint4*)(h1p + (long)s##k * 64 + l * 8);

#define SLOT_STEP(k) { \
    float ee = v##k ? __expf(lrelu(bf2f(ab##k) + adh)) : 0.f; \
    den += ee; \
    acc[0] += ee * bflo(pv##k.x); acc[1] += ee * bfhi(pv##k.x); \
    acc[2] += ee * bflo(pv##k.y); acc[3] += ee * bfhi(pv##k.y); \
    acc[4] += ee * bflo(pv##k.z); acc[5] += ee * bfhi(pv##k.z); \
    acc[6] += ee * bflo(pv##k.w); acc[7] += ee * bfhi(pv##k.w); \
    v##k = (j + 5 + k) < dgl; \
    int sn = v##k ? lds_src[beg + j + 5 + k] : 0; \
    ab##k = a1sh[(long)sn * 8 + l]; \
    pv##k = *(const uint4*)(h1p + (long)sn * 64 + l * 8); }

__global__ __launch_bounds__(512) void k_gat1(
    const unsigned* __restrict__ gbuf, const int* __restrict__ bcur,
    int* __restrict__ rowptr, int* __restrict__ ecol,
    const unsigned short* __restrict__ a1sh, const float* __restrict__ a1d,
    const unsigned short* __restrict__ h1p, const float* __restrict__ bias1,
    const float* __restrict__ wv,
    float2* __restrict__ sg2, float* __restrict__ a2dv)
{
    __shared__ int lds_src[BCAP];
    __shared__ int hist[NDB], excl[NDB + 1], cnt2[NDB];
    __shared__ int red[512];
    const int t = threadIdx.x;
    const int b = blockIdx.x;
    const int d0 = b << BSH;
    const int nloc = (N_NODES - d0 < NDB) ? (N_NODES - d0) : NDB;
    int cntr = bcur[b];
    const int cnt = cntr < BCAP ? cntr : BCAP;

    // ---- base = sum of bcur[0..b) (tree reduce over strided partials) ----
    int partial = 0;
    for (int i = t; i < b; i += 512) partial += bcur[i];
    red[t] = partial;
    __syncthreads();
    for (int off = 256; off > 0; off >>= 1) {
        if (t < off) red[t] += red[t + off];
        __syncthreads();
    }
    const int base = red[0];
    __syncthreads();

    // ---- local histogram over 128 dsts ----
    if (t < NDB) { hist[t] = 0; cnt2[t] = 0; }
    __syncthreads();
    const unsigned* eb = gbuf + (long)b * BCAP;
    for (int i = t; i < cnt; i += 512) atomicAdd(&hist[eb[i] >> 17], 1);
    __syncthreads();
    // ---- parallel exclusive scan of hist[128] ----
    {
        int v = (t < NDB) ? hist[t] : 0;
        if (t < NDB) red[t] = v;
        __syncthreads();
        for (int off = 1; off < NDB; off <<= 1) {
            int a = (t < NDB && t >= off) ? red[t - off] : 0;
            __syncthreads();
            if (t < NDB) red[t] += a;
            __syncthreads();
        }
        if (t < nloc) excl[t] = red[t] - v;
        if (t == 0) excl[nloc] = cnt;
    }
    __syncthreads();
    // ---- rowptr + LDS scatter (src only) + ecol flush (for gat2) ----
    if (t < nloc) rowptr[d0 + t] = base + excl[t];
    if (b == NBUCK - 1 && t == 0) rowptr[N_NODES] = base + cnt;
    for (int i = t; i < cnt; i += 512) {
        unsigned pr = eb[i];
        int dl = (int)(pr >> 17);
        int slot = excl[dl] + atomicAdd(&cnt2[dl], 1);
        lds_src[slot] = (int)(pr & SRC_MASK);
    }
    __syncthreads();
    for (int i = t; i < cnt; i += 512) ecol[base + i] = lds_src[i];

    // ---- gather: lane l = head l (owns 8 ch); 5-deep pipeline; edges in LDS.
    //      den/acc head-local -> no cross-group reduction per dst. ----
    const int l = t & 7;
    const int gid = t >> 3;                  // 0..63 groups
    for (int dl = gid; dl < nloc; dl += 64) {
        const int dst = d0 + dl;
        const int beg = excl[dl];
        const int dgl = excl[dl + 1] - beg;  // >= 1 (self-loop)
        const float adh = a1d[(long)dst * 8 + l];

        float acc[8] = {0.f,0.f,0.f,0.f,0.f,0.f,0.f,0.f};
        float den = 0.f;

        SLOT_INIT(0) SLOT_INIT(1) SLOT_INIT(2) SLOT_INIT(3) SLOT_INIT(4)

        for (int j = 0; j < dgl; j += 5) {
            SLOT_STEP(0) SLOT_STEP(1) SLOT_STEP(2) SLOT_STEP(3) SLOT_STEP(4)
        }

        // ---- epilogue: normalize, bias, ELU, project to (pg, ps, pd) ----
        const float inv = 1.f / den;
        float pg = 0.f, ps = 0.f, pd = 0.f;
        #pragma unroll
        for (int k = 0; k < 8; ++k) {
            float vv = acc[k] * inv + bias1[l * 8 + k];
            vv = vv > 0.f ? vv : (__expf(vv) - 1.f);      // elu -> x2 channel
            pg += vv * wv[l * 8 + k];
            ps += vv * wv[64 + l * 8 + k];
            pd += vv * wv[128 + l * 8 + k];
        }
        #pragma unroll
        for (int off = 1; off < 8; off <<= 1) {           // reduce over 8 head-lanes
            pg += __shfl_xor(pg, off, 64);
            ps += __shfl_xor(ps, off, 64);
            pd += __shfl_xor(pd, off, 64);
        }
        if (l == 0) { sg2[dst] = make_float2(ps, pg); a2dv[dst] = pd; }
    }
}

// ---- conv2 + pool + linear (persistent, 16-lane subgroups; r2-exact) -----
__global__ __launch_bounds__(256) void k_gat2(
    const int* __restrict__ rowptr, const int* __restrict__ ecol,
    const float2* __restrict__ sg2, const float* __restrict__ a2dv,
    const float* __restrict__ wv, const int* __restrict__ batch,
    float* __restrict__ out)
{
    const int sl = threadIdx.x & 15;
    const int sgid = ((blockIdx.x * 256 + threadIdx.x) >> 4);
    const int NS = G2_BLOCKS * 16;
    const int per = (N_NODES + NS - 1) / NS;
    const int n0 = sgid * per;
    const int n1 = min(n0 + per, N_NODES);
    const float bc = wv[192];

    float accg = 0.f;
    int curg = -1;
    for (int n = n0; n < n1; ++n) {
        const int beg = rowptr[n], end = rowptr[n + 1];
        const float adv = a2dv[n];
        float num = 0.f, den = 0.f;
        for (int j = beg + sl; j < end; j += 16) {
            int s = ecol[j];
            float2 v = sg2[s];
            float ee = __expf(lrelu(v.x + adv));
            den += ee;
            num += ee * v.y;
        }
        #pragma unroll
        for (int off = 1; off < 16; off <<= 1) {
            den += __shfl_xor(den, off, 64);
            num += __shfl_xor(num, off, 64);
        }
        if (sl == 0) {
            int gr = batch[n];
            if (gr != curg) {
                if (curg >= 0) atomAddF(out + curg, accg);
                curg = gr; accg = 0.f;
            }
            accg += num / den + bc;
        }
    }
    if (sl == 0 && curg >= 0) atomAddF(out + curg, accg);
}

extern "C" void kernel_launch(void* const* d_in, const int* in_sizes, int n_in,
                              void* d_out, int out_size, void* d_ws, size_t ws_size,
                              hipStream_t stream) {
    (void)in_sizes; (void)n_in; (void)out_size; (void)ws_size;
    const float* x     = (const float*)d_in[0];
    const int*   ei    = (const int*)d_in[1];
    const int*   batch = (const int*)d_in[2];
    const float* W1    = (const float*)d_in[3];
    const float* as1   = (const float*)d_in[4];
    const float* ad1   = (const float*)d_in[5];
    const float* b1    = (const float*)d_in[6];
    const float* W2    = (const float*)d_in[7];
    const float* as2   = (const float*)d_in[8];
    const float* ad2   = (const float*)d_in[9];
    const float* b2    = (const float*)d_in[10];
    const float* Wg    = (const float*)d_in[11];
    const float* bg    = (const float*)d_in[12];
    float* out = (float*)d_out;

    // ---- workspace layout (16-B aligned chunks; total ~35 MB) ----
    const long N = N_NODES;
    char* p = (char*)d_ws;
    int* rowptr = (int*)p;              p += (N + 4)        * sizeof(int);
    int* bcur   = (int*)p;              p += 1024           * sizeof(int);
    int* ecol   = (int*)p;              p += (long)ET       * sizeof(int);
    unsigned* gbuf = (unsigned*)p;      p += (long)NBUCK * BCAP * sizeof(unsigned);
    unsigned short* h1p  = (unsigned short*)p; p += N * 64  * sizeof(unsigned short);
    unsigned short* a1sh = (unsigned short*)p; p += N * 8   * sizeof(unsigned short);
    float* a1d  = (float*)p;            p += N * 8          * sizeof(float);
    float2* sg2 = (float2*)p;           p += N              * sizeof(float2);
    float* a2dv = (float*)p;            p += N              * sizeof(float);
    float* wv   = (float*)p;            p += 256            * sizeof(float);

    hipMemsetAsync(bcur, 0, NBUCK * sizeof(int), stream);
    // L1: CSR pass A + wv/out-init + conv1 features (co-scheduled)
    k_pre <<<PRE_GRID, 256, 0, stream>>>(ei, gbuf, bcur, x, W1, as1, ad1,
                                         W2, as2, ad2, Wg, b2, bg,
                                         h1p, a1sh, a1d, wv, out);
    // L2: CSR pass B + conv1 gather + projection (8-lane group per dst)
    k_gat1<<<NBUCK, 512, 0, stream>>>(gbuf, bcur, rowptr, ecol,
                                      a1sh, a1d, h1p, b1, wv, sg2, a2dv);
    // L3: conv2 + pool + linear
    k_gat2<<<G2_BLOCKS, 256, 0, stream>>>(rowptr, ecol, sg2, a2dv, wv, batch, out);
}